// Round 11
// baseline (427.386 us; speedup 1.0000x reference)
//
#include <hip/hip_runtime.h>
#include <cstdint>
#include <cstddef>

// N=50000 nodes, E=800000 edges, F_in=512, H=128, C=64.
// R11 = R0-exact pipeline (best measured, 358us) + pk2 gemm1 packing +
// agg1 launched 3x (idempotent) as a timing probe: agg1 = (total-358)/2.
constexpr int FIN = 512;
constexpr int HD  = 128;
constexpr int CD  = 64;

typedef __attribute__((ext_vector_type(8))) short short8;   // 8 bf16 = 4 VGPRs
typedef __attribute__((ext_vector_type(4))) float f32x4;    // MFMA acc

__device__ inline unsigned short f2bf(float f) {  // RNE fp32->bf16
  unsigned int u = __float_as_uint(f);
  u += 0x7fffu + ((u >> 16) & 1u);
  return (unsigned short)(u >> 16);
}
__device__ inline unsigned int pk2(float lo, float hi) {  // two bf16 in one dword
  return (unsigned int)f2bf(lo) | ((unsigned int)f2bf(hi) << 16);
}
__device__ inline float bf_lo(unsigned int v) { return __uint_as_float(v << 16); }
__device__ inline float bf_hi(unsigned int v) { return __uint_as_float(v & 0xffff0000u); }
__device__ inline float bf1(unsigned short v) { return __uint_as_float((unsigned int)v << 16); }

// ---------------- prep: weight cvt/transpose + zero cnt ----------------

__global__ __launch_bounds__(256) void prep(const float* __restrict__ W1,
                                            const float* __restrict__ W2,
                                            unsigned short* __restrict__ w1t,
                                            unsigned short* __restrict__ w2t,
                                            int* __restrict__ cnt, int n) {
  int idx = blockIdx.x * 256 + threadIdx.x;
  if (idx < FIN * HD) {
    int k = idx >> 7, c = idx & 127;
    w1t[(size_t)c * FIN + k] = f2bf(W1[idx]);
  } else if (idx < FIN * HD + HD * CD) {
    int j = idx - FIN * HD;
    int k = j >> 6, c = j & 63;
    w2t[(size_t)c * HD + k] = f2bf(W2[j]);
  }
  if (idx < n) cnt[idx] = 0;
}

// ---------------- hist ----------------

__global__ __launch_bounds__(256) void hist_kernel(const int* __restrict__ dst, int E,
                                                   int* __restrict__ cnt) {
  int i = blockIdx.x * 256 + threadIdx.x;
  if (i < E) atomicAdd(&cnt[dst[i]], 1);
}

// ---------------- deterministic 2-kernel scan (no inter-block sync) ----------------

__global__ __launch_bounds__(256) void scan_a(const int* __restrict__ cnt,
                                              int* __restrict__ bs, int n) {
  __shared__ int sh[256];
  int t = threadIdx.x;
  int base = blockIdx.x * 2048;
  int s = 0;
#pragma unroll
  for (int j = 0; j < 8; ++j) {
    int idx = base + j * 256 + t;
    if (idx < n) s += cnt[idx];
  }
  sh[t] = s;
  __syncthreads();
  for (int o = 128; o > 0; o >>= 1) {
    if (t < o) sh[t] += sh[t + o];
    __syncthreads();
  }
  if (t == 0) bs[blockIdx.x] = sh[0];
}

__global__ __launch_bounds__(256) void scan_c(const int* __restrict__ cnt,
                                              const int* __restrict__ bs,
                                              int* __restrict__ off,
                                              int* __restrict__ cur, int n) {
  __shared__ int sh[256];
  __shared__ int sbase;
  const int t   = threadIdx.x;
  const int bid = blockIdx.x;
  if (t < 64) {  // block offset = sum of earlier blocks' sums (bid <= 63)
    int v = (t < bid) ? bs[t] : 0;
#pragma unroll
    for (int o = 32; o > 0; o >>= 1) v += __shfl_xor(v, o, 64);
    if (t == 0) sbase = v;
  }
  const int base = bid * 2048 + t * 8;
  int v[8];
  int local = 0;
#pragma unroll
  for (int j = 0; j < 8; ++j) {
    v[j] = (base + j < n) ? cnt[base + j] : 0;
    local += v[j];
  }
  sh[t] = local;
  __syncthreads();
  for (int o = 1; o < 256; o <<= 1) {
    int u = (t >= o) ? sh[t - o] : 0;
    __syncthreads();
    sh[t] += u;
    __syncthreads();
  }
  int run = sbase + sh[t] - local;
#pragma unroll
  for (int j = 0; j < 8; ++j) {
    if (base + j < n) { off[base + j] = run; cur[base + j] = run; }
    run += v[j];
  }
}

// ---------------- scatter ----------------

__global__ __launch_bounds__(256) void scatter_kernel(const int* __restrict__ src,
                                                      const int* __restrict__ dst,
                                                      const float* __restrict__ ew, int E,
                                                      int* __restrict__ cur,
                                                      int2* __restrict__ sew) {
  int i = blockIdx.x * 256 + threadIdx.x;
  if (i < E) {
    int d = dst[i];
    int p = atomicAdd(&cur[d], 1);
    sew[p] = make_int2(src[i], __float_as_int(ew[i]));
  }
}

// ---------------- GEMM1 (MFMA bf16): h1b[M,128](bf16) = x @ W1 ----------------
// R0-measured shape: 128x128 tile / 256-thr block, BK=32, wave = 2x8 tiles.
// Only change vs R0: pk2 register packing (no tmp[16] array -> no scratch).

__global__ __launch_bounds__(256) void gemm1_mfma(const float* __restrict__ x,
                                                  const unsigned short* __restrict__ w1t,
                                                  unsigned short* __restrict__ h1b, int M) {
  __shared__ unsigned short As[128][40];
  __shared__ unsigned short Bs[128][40];
  const int t    = threadIdx.x;
  const int wave = t >> 6;
  const int lane = t & 63;
  const int l15  = lane & 15;
  const int quad = lane >> 4;
  const int m0   = blockIdx.x * 128;

  const int sr = t >> 1;        // staging row 0..127
  const int sk = (t & 1) * 16;  // staging k: 0 or 16

  const bool aok = (m0 + sr) < M;
  const float* xrow = x + (size_t)(m0 + sr) * FIN + sk;
  const unsigned short* brow = w1t + (size_t)sr * FIN + sk;

  f32x4 acc[2][8];
#pragma unroll
  for (int i = 0; i < 2; ++i)
#pragma unroll
    for (int j = 0; j < 8; ++j) acc[i][j] = (f32x4)0.f;

  for (int k0 = 0; k0 < FIN; k0 += 32) {
    float4 a0 = make_float4(0.f, 0.f, 0.f, 0.f), a1 = a0, a2 = a0, a3 = a0;
    if (aok) {
      a0 = *(const float4*)(xrow + k0);
      a1 = *(const float4*)(xrow + k0 + 4);
      a2 = *(const float4*)(xrow + k0 + 8);
      a3 = *(const float4*)(xrow + k0 + 12);
    }
    uint4 b0 = *(const uint4*)(brow + k0);
    uint4 b1 = *(const uint4*)(brow + k0 + 8);
    __syncthreads();
    uint4 av0, av1;   // register-only bf16 packing
    av0.x = pk2(a0.x, a0.y); av0.y = pk2(a0.z, a0.w);
    av0.z = pk2(a1.x, a1.y); av0.w = pk2(a1.z, a1.w);
    av1.x = pk2(a2.x, a2.y); av1.y = pk2(a2.z, a2.w);
    av1.z = pk2(a3.x, a3.y); av1.w = pk2(a3.z, a3.w);
    *(uint4*)&As[sr][sk]     = av0;
    *(uint4*)&As[sr][sk + 8] = av1;
    *(uint4*)&Bs[sr][sk]     = b0;
    *(uint4*)&Bs[sr][sk + 8] = b1;
    __syncthreads();
    short8 af0 = *(const short8*)&As[wave * 32 + l15][quad * 8];
    short8 af1 = *(const short8*)&As[wave * 32 + 16 + l15][quad * 8];
#pragma unroll
    for (int nt = 0; nt < 8; ++nt) {
      short8 bf = *(const short8*)&Bs[nt * 16 + l15][quad * 8];
      acc[0][nt] = __builtin_amdgcn_mfma_f32_16x16x32_bf16(af0, bf, acc[0][nt], 0, 0, 0);
      acc[1][nt] = __builtin_amdgcn_mfma_f32_16x16x32_bf16(af1, bf, acc[1][nt], 0, 0, 0);
    }
  }
#pragma unroll
  for (int mt = 0; mt < 2; ++mt) {
    const int row0 = m0 + wave * 32 + mt * 16 + quad * 4;
#pragma unroll
    for (int r = 0; r < 4; ++r) {
      int row = row0 + r;
      if (row < M) {
        unsigned short* orow = h1b + (size_t)row * HD + l15;
#pragma unroll
        for (int nt = 0; nt < 8; ++nt) orow[nt * 16] = f2bf(acc[mt][nt][r]);
      }
    }
  }
}

// ---------------- agg1: wave/node (max TLP), 8-deep unroll, bf16 in/out ----------------
// IDEMPOTENT: reads h1b/b1/dm/off/cnt/sew, writes only hbf. Launched 3x in
// R11 as a timing probe (identical output each time).

__global__ __launch_bounds__(256) void agg1_kernel(const unsigned int* __restrict__ h1b,
                                                   const float* __restrict__ b1,
                                                   const float* __restrict__ dm,
                                                   const int* __restrict__ off,
                                                   const int* __restrict__ cnt,
                                                   const int2* __restrict__ sew,
                                                   unsigned int* __restrict__ hbf, int N) {
  const int wave = threadIdx.x >> 6;
  const int lane = threadIdx.x & 63;
  const int node = blockIdx.x * 4 + wave;
  if (node >= N) return;
  const int start = off[node];
  const int deg   = cnt[node];
  const int2* ep  = sew + start;

  float a0 = 0.f, a1 = 0.f, c0 = 0.f, c1 = 0.f;
  float e0 = 0.f, e1 = 0.f, g0 = 0.f, g1 = 0.f;
  int e = 0;
  for (; e + 8 <= deg; e += 8) {
    int2 p0 = ep[e + 0], p1 = ep[e + 1], p2 = ep[e + 2], p3 = ep[e + 3];
    int2 p4 = ep[e + 4], p5 = ep[e + 5], p6 = ep[e + 6], p7 = ep[e + 7];
    unsigned int v0 = h1b[(size_t)p0.x * 64 + lane];
    unsigned int v1 = h1b[(size_t)p1.x * 64 + lane];
    unsigned int v2 = h1b[(size_t)p2.x * 64 + lane];
    unsigned int v3 = h1b[(size_t)p3.x * 64 + lane];
    unsigned int v4 = h1b[(size_t)p4.x * 64 + lane];
    unsigned int v5 = h1b[(size_t)p5.x * 64 + lane];
    unsigned int v6 = h1b[(size_t)p6.x * 64 + lane];
    unsigned int v7 = h1b[(size_t)p7.x * 64 + lane];
    float w0 = __int_as_float(p0.y), w1 = __int_as_float(p1.y);
    float w2 = __int_as_float(p2.y), w3 = __int_as_float(p3.y);
    float w4 = __int_as_float(p4.y), w5 = __int_as_float(p5.y);
    float w6 = __int_as_float(p6.y), w7 = __int_as_float(p7.y);
    a0 = fmaf(bf_lo(v0), w0, a0); a1 = fmaf(bf_hi(v0), w0, a1);
    c0 = fmaf(bf_lo(v1), w1, c0); c1 = fmaf(bf_hi(v1), w1, c1);
    e0 = fmaf(bf_lo(v2), w2, e0); e1 = fmaf(bf_hi(v2), w2, e1);
    g0 = fmaf(bf_lo(v3), w3, g0); g1 = fmaf(bf_hi(v3), w3, g1);
    a0 = fmaf(bf_lo(v4), w4, a0); a1 = fmaf(bf_hi(v4), w4, a1);
    c0 = fmaf(bf_lo(v5), w5, c0); c1 = fmaf(bf_hi(v5), w5, c1);
    e0 = fmaf(bf_lo(v6), w6, e0); e1 = fmaf(bf_hi(v6), w6, e1);
    g0 = fmaf(bf_lo(v7), w7, g0); g1 = fmaf(bf_hi(v7), w7, g1);
  }
  for (; e + 4 <= deg; e += 4) {
    int2 p0 = ep[e + 0], p1 = ep[e + 1], p2 = ep[e + 2], p3 = ep[e + 3];
    unsigned int v0 = h1b[(size_t)p0.x * 64 + lane];
    unsigned int v1 = h1b[(size_t)p1.x * 64 + lane];
    unsigned int v2 = h1b[(size_t)p2.x * 64 + lane];
    unsigned int v3 = h1b[(size_t)p3.x * 64 + lane];
    float w0 = __int_as_float(p0.y), w1 = __int_as_float(p1.y);
    float w2 = __int_as_float(p2.y), w3 = __int_as_float(p3.y);
    a0 = fmaf(bf_lo(v0), w0, a0); a1 = fmaf(bf_hi(v0), w0, a1);
    c0 = fmaf(bf_lo(v1), w1, c0); c1 = fmaf(bf_hi(v1), w1, c1);
    e0 = fmaf(bf_lo(v2), w2, e0); e1 = fmaf(bf_hi(v2), w2, e1);
    g0 = fmaf(bf_lo(v3), w3, g0); g1 = fmaf(bf_hi(v3), w3, g1);
  }
  for (; e < deg; ++e) {
    int2 p = ep[e];
    unsigned int v = h1b[(size_t)p.x * 64 + lane];
    float w = __int_as_float(p.y);
    a0 = fmaf(bf_lo(v), w, a0); a1 = fmaf(bf_hi(v), w, a1);
  }
  a0 += c0 + e0 + g0; a1 += c1 + e1 + g1;

  const int f0 = lane * 2;
  float2 bb = *(const float2*)(b1 + f0);
  float2 dd = *(const float2*)(dm + (size_t)node * HD + f0);
  float r0 = fmaxf(a0 + bb.x, 0.f) * ((dd.x >= 0.5f) ? 2.0f : 0.0f);
  float r1 = fmaxf(a1 + bb.y, 0.f) * ((dd.y >= 0.5f) ? 2.0f : 0.0f);
  hbf[(size_t)node * 64 + lane] = (unsigned int)f2bf(r0) | ((unsigned int)f2bf(r1) << 16);
}

// ---------------- GEMM2 (MFMA bf16): h2b[M,64](bf16) = h_bf[M,128] @ W2 ----------------

__global__ __launch_bounds__(256) void gemm2_mfma(const unsigned short* __restrict__ hbf,
                                                  const unsigned short* __restrict__ w2t,
                                                  unsigned short* __restrict__ h2b, int M) {
  __shared__ unsigned short As[128][40];
  __shared__ unsigned short Bs[64][40];
  const int t    = threadIdx.x;
  const int wave = t >> 6;
  const int lane = t & 63;
  const int l15  = lane & 15;
  const int quad = lane >> 4;
  const int m0   = blockIdx.x * 128;

  const int sr = t >> 1;        // A staging row 0..127
  const int sk = (t & 1) * 16;
  const int rb = t >> 2;        // B staging row 0..63
  const int kb = (t & 3) * 8;   // 4 threads x 8 ushorts = 32

  const bool aok = (m0 + sr) < M;
  const unsigned short* arow = hbf + (size_t)(m0 + sr) * HD + sk;
  const unsigned short* brow = w2t + (size_t)rb * HD + kb;

  f32x4 acc[2][4];
#pragma unroll
  for (int i = 0; i < 2; ++i)
#pragma unroll
    for (int j = 0; j < 4; ++j) acc[i][j] = (f32x4)0.f;

  for (int k0 = 0; k0 < HD; k0 += 32) {
    uint4 av0 = make_uint4(0, 0, 0, 0), av1 = av0;
    if (aok) {
      av0 = *(const uint4*)(arow + k0);
      av1 = *(const uint4*)(arow + k0 + 8);
    }
    uint4 bv = *(const uint4*)(brow + k0);   // 8 ushorts
    __syncthreads();
    *(uint4*)&As[sr][sk]     = av0;
    *(uint4*)&As[sr][sk + 8] = av1;
    *(uint4*)&Bs[rb][kb]     = bv;
    __syncthreads();
    short8 af0 = *(const short8*)&As[wave * 32 + l15][quad * 8];
    short8 af1 = *(const short8*)&As[wave * 32 + 16 + l15][quad * 8];
#pragma unroll
    for (int nt = 0; nt < 4; ++nt) {
      short8 bf = *(const short8*)&Bs[nt * 16 + l15][quad * 8];
      acc[0][nt] = __builtin_amdgcn_mfma_f32_16x16x32_bf16(af0, bf, acc[0][nt], 0, 0, 0);
      acc[1][nt] = __builtin_amdgcn_mfma_f32_16x16x32_bf16(af1, bf, acc[1][nt], 0, 0, 0);
    }
  }
#pragma unroll
  for (int mt = 0; mt < 2; ++mt) {
    const int row0 = m0 + wave * 32 + mt * 16 + quad * 4;
#pragma unroll
    for (int r = 0; r < 4; ++r) {
      int row = row0 + r;
      if (row < M) {
        unsigned short* orow = h2b + (size_t)row * CD + l15;
#pragma unroll
        for (int nt = 0; nt < 4; ++nt) orow[nt * 16] = f2bf(acc[mt][nt][r]);
      }
    }
  }
}

// ---------------- agg2 + bias + log_softmax: wave/node, 8-deep unroll ----------------

__global__ __launch_bounds__(256) void agg2_kernel(const unsigned short* __restrict__ h2b,
                                                   const float* __restrict__ b2,
                                                   const int* __restrict__ off,
                                                   const int* __restrict__ cnt,
                                                   const int2* __restrict__ sew,
                                                   float* __restrict__ out, int N) {
  const int wave = threadIdx.x >> 6;
  const int c    = threadIdx.x & 63;
  const int node = blockIdx.x * 4 + wave;
  if (node >= N) return;
  const int start = off[node];
  const int deg   = cnt[node];
  const int2* ep  = sew + start;

  float acc = b2[c], a1 = 0.f, a2 = 0.f, a3 = 0.f;
  int e = 0;
  for (; e + 8 <= deg; e += 8) {
    int2 p0 = ep[e + 0], p1 = ep[e + 1], p2 = ep[e + 2], p3 = ep[e + 3];
    int2 p4 = ep[e + 4], p5 = ep[e + 5], p6 = ep[e + 6], p7 = ep[e + 7];
    float v0 = bf1(h2b[(size_t)p0.x * CD + c]);
    float v1 = bf1(h2b[(size_t)p1.x * CD + c]);
    float v2 = bf1(h2b[(size_t)p2.x * CD + c]);
    float v3 = bf1(h2b[(size_t)p3.x * CD + c]);
    float v4 = bf1(h2b[(size_t)p4.x * CD + c]);
    float v5 = bf1(h2b[(size_t)p5.x * CD + c]);
    float v6 = bf1(h2b[(size_t)p6.x * CD + c]);
    float v7 = bf1(h2b[(size_t)p7.x * CD + c]);
    acc = fmaf(v0, __int_as_float(p0.y), acc);
    a1  = fmaf(v1, __int_as_float(p1.y), a1);
    a2  = fmaf(v2, __int_as_float(p2.y), a2);
    a3  = fmaf(v3, __int_as_float(p3.y), a3);
    acc = fmaf(v4, __int_as_float(p4.y), acc);
    a1  = fmaf(v5, __int_as_float(p5.y), a1);
    a2  = fmaf(v6, __int_as_float(p6.y), a2);
    a3  = fmaf(v7, __int_as_float(p7.y), a3);
  }
  for (; e + 4 <= deg; e += 4) {
    int2 p0 = ep[e + 0], p1 = ep[e + 1], p2 = ep[e + 2], p3 = ep[e + 3];
    float v0 = bf1(h2b[(size_t)p0.x * CD + c]);
    float v1 = bf1(h2b[(size_t)p1.x * CD + c]);
    float v2 = bf1(h2b[(size_t)p2.x * CD + c]);
    float v3 = bf1(h2b[(size_t)p3.x * CD + c]);
    acc = fmaf(v0, __int_as_float(p0.y), acc);
    a1  = fmaf(v1, __int_as_float(p1.y), a1);
    a2  = fmaf(v2, __int_as_float(p2.y), a2);
    a3  = fmaf(v3, __int_as_float(p3.y), a3);
  }
  for (; e < deg; ++e) {
    int2 p = ep[e];
    acc = fmaf(bf1(h2b[(size_t)p.x * CD + c]), __int_as_float(p.y), acc);
  }
  acc += a1 + a2 + a3;

  float m = acc;
#pragma unroll
  for (int o = 32; o > 0; o >>= 1) m = fmaxf(m, __shfl_xor(m, o, 64));
  float ex = __expf(acc - m);
  float ssum = ex;
#pragma unroll
  for (int o = 32; o > 0; o >>= 1) ssum += __shfl_xor(ssum, o, 64);
  out[(size_t)node * CD + c] = (acc - m) - __logf(ssum);
}

// ---------------- launch ----------------

extern "C" void kernel_launch(void* const* d_in, const int* in_sizes, int n_in,
                              void* d_out, int out_size, void* d_ws, size_t ws_size,
                              hipStream_t stream) {
  const float* x  = (const float*)d_in[0];
  const float* ew = (const float*)d_in[1];
  const float* W1 = (const float*)d_in[2];
  const float* b1 = (const float*)d_in[3];
  const float* W2 = (const float*)d_in[4];
  const float* b2 = (const float*)d_in[5];
  const float* dm = (const float*)d_in[6];
  const int*   ei = (const int*)d_in[7];
  float* out = (float*)d_out;

  const int E = in_sizes[1];
  const int N = in_sizes[6] / HD;
  const int* srcp = ei;
  const int* dstp = ei + E;
  const int nb = (N + 2047) / 2048;  // 25 scan blocks (<=64 supported by scan_c)

  uint8_t* w = (uint8_t*)d_ws;
  size_t o = 0;
  auto alloc = [&](size_t bytes) -> void* {
    void* p = w + o;
    o = (o + bytes + 255) & ~(size_t)255;
    return p;
  };
  int*   off    = (int*)alloc((size_t)N * 4);
  int*   cnt    = (int*)alloc((size_t)N * 4);
  int*   cur    = (int*)alloc((size_t)N * 4);
  int2*  sew    = (int2*)alloc((size_t)E * 8);
  unsigned short* h1b = (unsigned short*)alloc((size_t)N * HD * 2);
  unsigned int*   hbf = (unsigned int*)alloc((size_t)N * HD * 2);
  unsigned short* h2b = (unsigned short*)alloc((size_t)N * CD * 2);
  unsigned short* w1t = (unsigned short*)alloc((size_t)FIN * HD * 2);
  unsigned short* w2t = (unsigned short*)alloc((size_t)HD * CD * 2);
  int*   bsum   = (int*)alloc((size_t)nb * 4);

  const int prep_threads = FIN * HD + HD * CD;  // covers N zeroing too (73728 > 50000)
  prep<<<(prep_threads + 255) / 256, 256, 0, stream>>>(W1, W2, w1t, w2t, cnt, N);
  hist_kernel<<<(E + 255) / 256, 256, 0, stream>>>(dstp, E, cnt);
  gemm1_mfma<<<(N + 127) / 128, 256, 0, stream>>>(x, w1t, h1b, N);
  scan_a<<<nb, 256, 0, stream>>>(cnt, bsum, N);
  scan_c<<<nb, 256, 0, stream>>>(cnt, bsum, off, cur, N);
  scatter_kernel<<<(E + 255) / 256, 256, 0, stream>>>(srcp, dstp, ew, E, cur, sew);
  // agg1 launched 3x: idempotent (writes only hbf, same values each time).
  // Timing probe: agg1_dur = (total - 358us_baseline) / 2.
  agg1_kernel<<<(N + 3) / 4, 256, 0, stream>>>((const unsigned int*)h1b, b1, dm, off, cnt, sew, hbf, N);
  agg1_kernel<<<(N + 3) / 4, 256, 0, stream>>>((const unsigned int*)h1b, b1, dm, off, cnt, sew, hbf, N);
  agg1_kernel<<<(N + 3) / 4, 256, 0, stream>>>((const unsigned int*)h1b, b1, dm, off, cnt, sew, hbf, N);
  gemm2_mfma<<<(N + 127) / 128, 256, 0, stream>>>((const unsigned short*)hbf, w2t, h2b, N);
  agg2_kernel<<<(N + 3) / 4, 256, 0, stream>>>(h2b, b2, off, cnt, sew, out, N);
}

// Round 12
// 333.589 us; speedup vs baseline: 1.2812x; 1.2812x over previous
//
#include <hip/hip_runtime.h>
#include <cstdint>
#include <cstddef>

// N=50000 nodes, E=800000 edges, F_in=512, H=128, C=64.
// R12 = R0-exact pipeline + pk2 gemm1 packing + GRID-PARTITIONED hist||gemm1
// fusion (blocks [0,ngemm) = gemm tile, [ngemm,ngemm+nhist) = histogram).
// R11 probe measured agg1 ~= 34us (near BW ceiling); R7 showed serial-prologue
// fusion is wrong (adds hist latency to every block); grid partition overlaps
// the two independent workloads on different CUs instead.
constexpr int FIN = 512;
constexpr int HD  = 128;
constexpr int CD  = 64;

typedef __attribute__((ext_vector_type(8))) short short8;   // 8 bf16 = 4 VGPRs
typedef __attribute__((ext_vector_type(4))) float f32x4;    // MFMA acc

__device__ inline unsigned short f2bf(float f) {  // RNE fp32->bf16
  unsigned int u = __float_as_uint(f);
  u += 0x7fffu + ((u >> 16) & 1u);
  return (unsigned short)(u >> 16);
}
__device__ inline unsigned int pk2(float lo, float hi) {  // two bf16 in one dword
  return (unsigned int)f2bf(lo) | ((unsigned int)f2bf(hi) << 16);
}
__device__ inline float bf_lo(unsigned int v) { return __uint_as_float(v << 16); }
__device__ inline float bf_hi(unsigned int v) { return __uint_as_float(v & 0xffff0000u); }
__device__ inline float bf1(unsigned short v) { return __uint_as_float((unsigned int)v << 16); }

// ---------------- prep: weight cvt/transpose + zero cnt ----------------

__global__ __launch_bounds__(256) void prep(const float* __restrict__ W1,
                                            const float* __restrict__ W2,
                                            unsigned short* __restrict__ w1t,
                                            unsigned short* __restrict__ w2t,
                                            int* __restrict__ cnt, int n) {
  int idx = blockIdx.x * 256 + threadIdx.x;
  if (idx < FIN * HD) {
    int k = idx >> 7, c = idx & 127;
    w1t[(size_t)c * FIN + k] = f2bf(W1[idx]);
  } else if (idx < FIN * HD + HD * CD) {
    int j = idx - FIN * HD;
    int k = j >> 6, c = j & 63;
    w2t[(size_t)c * HD + k] = f2bf(W2[j]);
  }
  if (idx < n) cnt[idx] = 0;
}

// ---------------- deterministic 2-kernel scan (no inter-block sync) ----------------

__global__ __launch_bounds__(256) void scan_a(const int* __restrict__ cnt,
                                              int* __restrict__ bs, int n) {
  __shared__ int sh[256];
  int t = threadIdx.x;
  int base = blockIdx.x * 2048;
  int s = 0;
#pragma unroll
  for (int j = 0; j < 8; ++j) {
    int idx = base + j * 256 + t;
    if (idx < n) s += cnt[idx];
  }
  sh[t] = s;
  __syncthreads();
  for (int o = 128; o > 0; o >>= 1) {
    if (t < o) sh[t] += sh[t + o];
    __syncthreads();
  }
  if (t == 0) bs[blockIdx.x] = sh[0];
}

__global__ __launch_bounds__(256) void scan_c(const int* __restrict__ cnt,
                                              const int* __restrict__ bs,
                                              int* __restrict__ off,
                                              int* __restrict__ cur, int n) {
  __shared__ int sh[256];
  __shared__ int sbase;
  const int t   = threadIdx.x;
  const int bid = blockIdx.x;
  if (t < 64) {  // block offset = sum of earlier blocks' sums (bid <= 63)
    int v = (t < bid) ? bs[t] : 0;
#pragma unroll
    for (int o = 32; o > 0; o >>= 1) v += __shfl_xor(v, o, 64);
    if (t == 0) sbase = v;
  }
  const int base = bid * 2048 + t * 8;
  int v[8];
  int local = 0;
#pragma unroll
  for (int j = 0; j < 8; ++j) {
    v[j] = (base + j < n) ? cnt[base + j] : 0;
    local += v[j];
  }
  sh[t] = local;
  __syncthreads();
  for (int o = 1; o < 256; o <<= 1) {
    int u = (t >= o) ? sh[t - o] : 0;
    __syncthreads();
    sh[t] += u;
    __syncthreads();
  }
  int run = sbase + sh[t] - local;
#pragma unroll
  for (int j = 0; j < 8; ++j) {
    if (base + j < n) { off[base + j] = run; cur[base + j] = run; }
    run += v[j];
  }
}

// ---------------- scatter ----------------

__global__ __launch_bounds__(256) void scatter_kernel(const int* __restrict__ src,
                                                      const int* __restrict__ dst,
                                                      const float* __restrict__ ew, int E,
                                                      int* __restrict__ cur,
                                                      int2* __restrict__ sew) {
  int i = blockIdx.x * 256 + threadIdx.x;
  if (i < E) {
    int d = dst[i];
    int p = atomicAdd(&cur[d], 1);
    sew[p] = make_int2(src[i], __float_as_int(ew[i]));
  }
}

// ---------------- GEMM1 || hist (grid-partitioned) ----------------
// blocks [0, ngemm): h1b[M,128](bf16) = x @ W1, 128x128 tile / BK=32 (R0 shape).
// blocks [ngemm, ngemm+nhist): 1-atomic-per-thread edge histogram.
// gemm blocks dispatch first (low bids = long pole); hist blocks fill the
// remaining per-CU residency and overlap on separate CUs/SIMDs.

__global__ __launch_bounds__(256) void gemm1_hist(const float* __restrict__ x,
                                                  const unsigned short* __restrict__ w1t,
                                                  unsigned short* __restrict__ h1b, int M,
                                                  const int* __restrict__ dst, int E,
                                                  int* __restrict__ cnt, int ngemm) {
  __shared__ unsigned short As[128][40];
  __shared__ unsigned short Bs[128][40];

  if ((int)blockIdx.x >= ngemm) {   // ---- hist role (uniform per block) ----
    int i = (blockIdx.x - ngemm) * 256 + threadIdx.x;
    if (i < E) atomicAdd(&cnt[dst[i]], 1);
    return;
  }

  // ---- gemm role ----
  const int t    = threadIdx.x;
  const int wave = t >> 6;
  const int lane = t & 63;
  const int l15  = lane & 15;
  const int quad = lane >> 4;
  const int m0   = blockIdx.x * 128;

  const int sr = t >> 1;        // staging row 0..127
  const int sk = (t & 1) * 16;  // staging k: 0 or 16

  const bool aok = (m0 + sr) < M;
  const float* xrow = x + (size_t)(m0 + sr) * FIN + sk;
  const unsigned short* brow = w1t + (size_t)sr * FIN + sk;

  f32x4 acc[2][8];
#pragma unroll
  for (int i = 0; i < 2; ++i)
#pragma unroll
    for (int j = 0; j < 8; ++j) acc[i][j] = (f32x4)0.f;

  for (int k0 = 0; k0 < FIN; k0 += 32) {
    float4 a0 = make_float4(0.f, 0.f, 0.f, 0.f), a1 = a0, a2 = a0, a3 = a0;
    if (aok) {
      a0 = *(const float4*)(xrow + k0);
      a1 = *(const float4*)(xrow + k0 + 4);
      a2 = *(const float4*)(xrow + k0 + 8);
      a3 = *(const float4*)(xrow + k0 + 12);
    }
    uint4 b0 = *(const uint4*)(brow + k0);
    uint4 b1 = *(const uint4*)(brow + k0 + 8);
    __syncthreads();
    uint4 av0, av1;   // register-only bf16 packing (no scratch array)
    av0.x = pk2(a0.x, a0.y); av0.y = pk2(a0.z, a0.w);
    av0.z = pk2(a1.x, a1.y); av0.w = pk2(a1.z, a1.w);
    av1.x = pk2(a2.x, a2.y); av1.y = pk2(a2.z, a2.w);
    av1.z = pk2(a3.x, a3.y); av1.w = pk2(a3.z, a3.w);
    *(uint4*)&As[sr][sk]     = av0;
    *(uint4*)&As[sr][sk + 8] = av1;
    *(uint4*)&Bs[sr][sk]     = b0;
    *(uint4*)&Bs[sr][sk + 8] = b1;
    __syncthreads();
    short8 af0 = *(const short8*)&As[wave * 32 + l15][quad * 8];
    short8 af1 = *(const short8*)&As[wave * 32 + 16 + l15][quad * 8];
#pragma unroll
    for (int nt = 0; nt < 8; ++nt) {
      short8 bf = *(const short8*)&Bs[nt * 16 + l15][quad * 8];
      acc[0][nt] = __builtin_amdgcn_mfma_f32_16x16x32_bf16(af0, bf, acc[0][nt], 0, 0, 0);
      acc[1][nt] = __builtin_amdgcn_mfma_f32_16x16x32_bf16(af1, bf, acc[1][nt], 0, 0, 0);
    }
  }
#pragma unroll
  for (int mt = 0; mt < 2; ++mt) {
    const int row0 = m0 + wave * 32 + mt * 16 + quad * 4;
#pragma unroll
    for (int r = 0; r < 4; ++r) {
      int row = row0 + r;
      if (row < M) {
        unsigned short* orow = h1b + (size_t)row * HD + l15;
#pragma unroll
        for (int nt = 0; nt < 8; ++nt) orow[nt * 16] = f2bf(acc[mt][nt][r]);
      }
    }
  }
}

// ---------------- agg1: wave/node (max TLP), 8-deep unroll, bf16 in/out ----------------

__global__ __launch_bounds__(256) void agg1_kernel(const unsigned int* __restrict__ h1b,
                                                   const float* __restrict__ b1,
                                                   const float* __restrict__ dm,
                                                   const int* __restrict__ off,
                                                   const int* __restrict__ cnt,
                                                   const int2* __restrict__ sew,
                                                   unsigned int* __restrict__ hbf, int N) {
  const int wave = threadIdx.x >> 6;
  const int lane = threadIdx.x & 63;
  const int node = blockIdx.x * 4 + wave;
  if (node >= N) return;
  const int start = off[node];
  const int deg   = cnt[node];
  const int2* ep  = sew + start;

  float a0 = 0.f, a1 = 0.f, c0 = 0.f, c1 = 0.f;
  float e0 = 0.f, e1 = 0.f, g0 = 0.f, g1 = 0.f;
  int e = 0;
  for (; e + 8 <= deg; e += 8) {
    int2 p0 = ep[e + 0], p1 = ep[e + 1], p2 = ep[e + 2], p3 = ep[e + 3];
    int2 p4 = ep[e + 4], p5 = ep[e + 5], p6 = ep[e + 6], p7 = ep[e + 7];
    unsigned int v0 = h1b[(size_t)p0.x * 64 + lane];
    unsigned int v1 = h1b[(size_t)p1.x * 64 + lane];
    unsigned int v2 = h1b[(size_t)p2.x * 64 + lane];
    unsigned int v3 = h1b[(size_t)p3.x * 64 + lane];
    unsigned int v4 = h1b[(size_t)p4.x * 64 + lane];
    unsigned int v5 = h1b[(size_t)p5.x * 64 + lane];
    unsigned int v6 = h1b[(size_t)p6.x * 64 + lane];
    unsigned int v7 = h1b[(size_t)p7.x * 64 + lane];
    float w0 = __int_as_float(p0.y), w1 = __int_as_float(p1.y);
    float w2 = __int_as_float(p2.y), w3 = __int_as_float(p3.y);
    float w4 = __int_as_float(p4.y), w5 = __int_as_float(p5.y);
    float w6 = __int_as_float(p6.y), w7 = __int_as_float(p7.y);
    a0 = fmaf(bf_lo(v0), w0, a0); a1 = fmaf(bf_hi(v0), w0, a1);
    c0 = fmaf(bf_lo(v1), w1, c0); c1 = fmaf(bf_hi(v1), w1, c1);
    e0 = fmaf(bf_lo(v2), w2, e0); e1 = fmaf(bf_hi(v2), w2, e1);
    g0 = fmaf(bf_lo(v3), w3, g0); g1 = fmaf(bf_hi(v3), w3, g1);
    a0 = fmaf(bf_lo(v4), w4, a0); a1 = fmaf(bf_hi(v4), w4, a1);
    c0 = fmaf(bf_lo(v5), w5, c0); c1 = fmaf(bf_hi(v5), w5, c1);
    e0 = fmaf(bf_lo(v6), w6, e0); e1 = fmaf(bf_hi(v6), w6, e1);
    g0 = fmaf(bf_lo(v7), w7, g0); g1 = fmaf(bf_hi(v7), w7, g1);
  }
  for (; e + 4 <= deg; e += 4) {
    int2 p0 = ep[e + 0], p1 = ep[e + 1], p2 = ep[e + 2], p3 = ep[e + 3];
    unsigned int v0 = h1b[(size_t)p0.x * 64 + lane];
    unsigned int v1 = h1b[(size_t)p1.x * 64 + lane];
    unsigned int v2 = h1b[(size_t)p2.x * 64 + lane];
    unsigned int v3 = h1b[(size_t)p3.x * 64 + lane];
    float w0 = __int_as_float(p0.y), w1 = __int_as_float(p1.y);
    float w2 = __int_as_float(p2.y), w3 = __int_as_float(p3.y);
    a0 = fmaf(bf_lo(v0), w0, a0); a1 = fmaf(bf_hi(v0), w0, a1);
    c0 = fmaf(bf_lo(v1), w1, c0); c1 = fmaf(bf_hi(v1), w1, c1);
    e0 = fmaf(bf_lo(v2), w2, e0); e1 = fmaf(bf_hi(v2), w2, e1);
    g0 = fmaf(bf_lo(v3), w3, g0); g1 = fmaf(bf_hi(v3), w3, g1);
  }
  for (; e < deg; ++e) {
    int2 p = ep[e];
    unsigned int v = h1b[(size_t)p.x * 64 + lane];
    float w = __int_as_float(p.y);
    a0 = fmaf(bf_lo(v), w, a0); a1 = fmaf(bf_hi(v), w, a1);
  }
  a0 += c0 + e0 + g0; a1 += c1 + e1 + g1;

  const int f0 = lane * 2;
  float2 bb = *(const float2*)(b1 + f0);
  float2 dd = *(const float2*)(dm + (size_t)node * HD + f0);
  float r0 = fmaxf(a0 + bb.x, 0.f) * ((dd.x >= 0.5f) ? 2.0f : 0.0f);
  float r1 = fmaxf(a1 + bb.y, 0.f) * ((dd.y >= 0.5f) ? 2.0f : 0.0f);
  hbf[(size_t)node * 64 + lane] = (unsigned int)f2bf(r0) | ((unsigned int)f2bf(r1) << 16);
}

// ---------------- GEMM2 (MFMA bf16): h2b[M,64](bf16) = h_bf[M,128] @ W2 ----------------

__global__ __launch_bounds__(256) void gemm2_mfma(const unsigned short* __restrict__ hbf,
                                                  const unsigned short* __restrict__ w2t,
                                                  unsigned short* __restrict__ h2b, int M) {
  __shared__ unsigned short As[128][40];
  __shared__ unsigned short Bs[64][40];
  const int t    = threadIdx.x;
  const int wave = t >> 6;
  const int lane = t & 63;
  const int l15  = lane & 15;
  const int quad = lane >> 4;
  const int m0   = blockIdx.x * 128;

  const int sr = t >> 1;        // A staging row 0..127
  const int sk = (t & 1) * 16;
  const int rb = t >> 2;        // B staging row 0..63
  const int kb = (t & 3) * 8;   // 4 threads x 8 ushorts = 32

  const bool aok = (m0 + sr) < M;
  const unsigned short* arow = hbf + (size_t)(m0 + sr) * HD + sk;
  const unsigned short* brow = w2t + (size_t)rb * HD + kb;

  f32x4 acc[2][4];
#pragma unroll
  for (int i = 0; i < 2; ++i)
#pragma unroll
    for (int j = 0; j < 4; ++j) acc[i][j] = (f32x4)0.f;

  for (int k0 = 0; k0 < HD; k0 += 32) {
    uint4 av0 = make_uint4(0, 0, 0, 0), av1 = av0;
    if (aok) {
      av0 = *(const uint4*)(arow + k0);
      av1 = *(const uint4*)(arow + k0 + 8);
    }
    uint4 bv = *(const uint4*)(brow + k0);   // 8 ushorts
    __syncthreads();
    *(uint4*)&As[sr][sk]     = av0;
    *(uint4*)&As[sr][sk + 8] = av1;
    *(uint4*)&Bs[rb][kb]     = bv;
    __syncthreads();
    short8 af0 = *(const short8*)&As[wave * 32 + l15][quad * 8];
    short8 af1 = *(const short8*)&As[wave * 32 + 16 + l15][quad * 8];
#pragma unroll
    for (int nt = 0; nt < 4; ++nt) {
      short8 bf = *(const short8*)&Bs[nt * 16 + l15][quad * 8];
      acc[0][nt] = __builtin_amdgcn_mfma_f32_16x16x32_bf16(af0, bf, acc[0][nt], 0, 0, 0);
      acc[1][nt] = __builtin_amdgcn_mfma_f32_16x16x32_bf16(af1, bf, acc[1][nt], 0, 0, 0);
    }
  }
#pragma unroll
  for (int mt = 0; mt < 2; ++mt) {
    const int row0 = m0 + wave * 32 + mt * 16 + quad * 4;
#pragma unroll
    for (int r = 0; r < 4; ++r) {
      int row = row0 + r;
      if (row < M) {
        unsigned short* orow = h2b + (size_t)row * CD + l15;
#pragma unroll
        for (int nt = 0; nt < 4; ++nt) orow[nt * 16] = f2bf(acc[mt][nt][r]);
      }
    }
  }
}

// ---------------- agg2 + bias + log_softmax: wave/node, 8-deep unroll ----------------

__global__ __launch_bounds__(256) void agg2_kernel(const unsigned short* __restrict__ h2b,
                                                   const float* __restrict__ b2,
                                                   const int* __restrict__ off,
                                                   const int* __restrict__ cnt,
                                                   const int2* __restrict__ sew,
                                                   float* __restrict__ out, int N) {
  const int wave = threadIdx.x >> 6;
  const int c    = threadIdx.x & 63;
  const int node = blockIdx.x * 4 + wave;
  if (node >= N) return;
  const int start = off[node];
  const int deg   = cnt[node];
  const int2* ep  = sew + start;

  float acc = b2[c], a1 = 0.f, a2 = 0.f, a3 = 0.f;
  int e = 0;
  for (; e + 8 <= deg; e += 8) {
    int2 p0 = ep[e + 0], p1 = ep[e + 1], p2 = ep[e + 2], p3 = ep[e + 3];
    int2 p4 = ep[e + 4], p5 = ep[e + 5], p6 = ep[e + 6], p7 = ep[e + 7];
    float v0 = bf1(h2b[(size_t)p0.x * CD + c]);
    float v1 = bf1(h2b[(size_t)p1.x * CD + c]);
    float v2 = bf1(h2b[(size_t)p2.x * CD + c]);
    float v3 = bf1(h2b[(size_t)p3.x * CD + c]);
    float v4 = bf1(h2b[(size_t)p4.x * CD + c]);
    float v5 = bf1(h2b[(size_t)p5.x * CD + c]);
    float v6 = bf1(h2b[(size_t)p6.x * CD + c]);
    float v7 = bf1(h2b[(size_t)p7.x * CD + c]);
    acc = fmaf(v0, __int_as_float(p0.y), acc);
    a1  = fmaf(v1, __int_as_float(p1.y), a1);
    a2  = fmaf(v2, __int_as_float(p2.y), a2);
    a3  = fmaf(v3, __int_as_float(p3.y), a3);
    acc = fmaf(v4, __int_as_float(p4.y), acc);
    a1  = fmaf(v5, __int_as_float(p5.y), a1);
    a2  = fmaf(v6, __int_as_float(p6.y), a2);
    a3  = fmaf(v7, __int_as_float(p7.y), a3);
  }
  for (; e + 4 <= deg; e += 4) {
    int2 p0 = ep[e + 0], p1 = ep[e + 1], p2 = ep[e + 2], p3 = ep[e + 3];
    float v0 = bf1(h2b[(size_t)p0.x * CD + c]);
    float v1 = bf1(h2b[(size_t)p1.x * CD + c]);
    float v2 = bf1(h2b[(size_t)p2.x * CD + c]);
    float v3 = bf1(h2b[(size_t)p3.x * CD + c]);
    acc = fmaf(v0, __int_as_float(p0.y), acc);
    a1  = fmaf(v1, __int_as_float(p1.y), a1);
    a2  = fmaf(v2, __int_as_float(p2.y), a2);
    a3  = fmaf(v3, __int_as_float(p3.y), a3);
  }
  for (; e < deg; ++e) {
    int2 p = ep[e];
    acc = fmaf(bf1(h2b[(size_t)p.x * CD + c]), __int_as_float(p.y), acc);
  }
  acc += a1 + a2 + a3;

  float m = acc;
#pragma unroll
  for (int o = 32; o > 0; o >>= 1) m = fmaxf(m, __shfl_xor(m, o, 64));
  float ex = __expf(acc - m);
  float ssum = ex;
#pragma unroll
  for (int o = 32; o > 0; o >>= 1) ssum += __shfl_xor(ssum, o, 64);
  out[(size_t)node * CD + c] = (acc - m) - __logf(ssum);
}

// ---------------- launch ----------------

extern "C" void kernel_launch(void* const* d_in, const int* in_sizes, int n_in,
                              void* d_out, int out_size, void* d_ws, size_t ws_size,
                              hipStream_t stream) {
  const float* x  = (const float*)d_in[0];
  const float* ew = (const float*)d_in[1];
  const float* W1 = (const float*)d_in[2];
  const float* b1 = (const float*)d_in[3];
  const float* W2 = (const float*)d_in[4];
  const float* b2 = (const float*)d_in[5];
  const float* dm = (const float*)d_in[6];
  const int*   ei = (const int*)d_in[7];
  float* out = (float*)d_out;

  const int E = in_sizes[1];
  const int N = in_sizes[6] / HD;
  const int* srcp = ei;
  const int* dstp = ei + E;
  const int nb = (N + 2047) / 2048;  // 25 scan blocks (<=64 supported by scan_c)

  uint8_t* w = (uint8_t*)d_ws;
  size_t o = 0;
  auto alloc = [&](size_t bytes) -> void* {
    void* p = w + o;
    o = (o + bytes + 255) & ~(size_t)255;
    return p;
  };
  int*   off    = (int*)alloc((size_t)N * 4);
  int*   cnt    = (int*)alloc((size_t)N * 4);
  int*   cur    = (int*)alloc((size_t)N * 4);
  int2*  sew    = (int2*)alloc((size_t)E * 8);
  unsigned short* h1b = (unsigned short*)alloc((size_t)N * HD * 2);
  unsigned int*   hbf = (unsigned int*)alloc((size_t)N * HD * 2);
  unsigned short* h2b = (unsigned short*)alloc((size_t)N * CD * 2);
  unsigned short* w1t = (unsigned short*)alloc((size_t)FIN * HD * 2);
  unsigned short* w2t = (unsigned short*)alloc((size_t)HD * CD * 2);
  int*   bsum   = (int*)alloc((size_t)nb * 4);

  const int prep_threads = FIN * HD + HD * CD;  // covers N zeroing too (73728 > 50000)
  prep<<<(prep_threads + 255) / 256, 256, 0, stream>>>(W1, W2, w1t, w2t, cnt, N);
  const int ngemm = (N + 127) / 128;   // 391 gemm blocks (dispatch first)
  const int nhist = (E + 255) / 256;   // 3125 hist blocks (fill residency)
  gemm1_hist<<<ngemm + nhist, 256, 0, stream>>>(x, w1t, h1b, N, dstp, E, cnt, ngemm);
  scan_a<<<nb, 256, 0, stream>>>(cnt, bsum, N);
  scan_c<<<nb, 256, 0, stream>>>(cnt, bsum, off, cur, N);
  scatter_kernel<<<(E + 255) / 256, 256, 0, stream>>>(srcp, dstp, ew, E, cur, sew);
  agg1_kernel<<<(N + 3) / 4, 256, 0, stream>>>((const unsigned int*)h1b, b1, dm, off, cnt, sew, hbf, N);
  gemm2_mfma<<<(N + 127) / 128, 256, 0, stream>>>((const unsigned short*)hbf, w2t, h2b, N);
  agg2_kernel<<<(N + 3) / 4, 256, 0, stream>>>(h2b, b2, off, cnt, sew, out, N);
}

// Round 13
// 330.157 us; speedup vs baseline: 1.2945x; 1.0104x over previous
//
#include <hip/hip_runtime.h>
#include <cstdint>
#include <cstddef>

// N=50000 nodes, E=800000 edges, F_in=512, H=128, C=64.
// R13 = R12 (gemm1||hist grid-partition, 333.6us) + second application of the
// partition pattern: gemm1's rows split across two dispatches, the second
// half co-scheduled with scatter so scatter's ~25-30us hides under it.
// Chain: prep -> [gemm1a||hist] -> scan_a -> scan_c -> [gemm1b||scatter]
//        -> agg1 -> gemm2 -> agg2.
constexpr int FIN = 512;
constexpr int HD  = 128;
constexpr int CD  = 64;

typedef __attribute__((ext_vector_type(8))) short short8;   // 8 bf16 = 4 VGPRs
typedef __attribute__((ext_vector_type(4))) float f32x4;    // MFMA acc

__device__ inline unsigned short f2bf(float f) {  // RNE fp32->bf16
  unsigned int u = __float_as_uint(f);
  u += 0x7fffu + ((u >> 16) & 1u);
  return (unsigned short)(u >> 16);
}
__device__ inline unsigned int pk2(float lo, float hi) {  // two bf16 in one dword
  return (unsigned int)f2bf(lo) | ((unsigned int)f2bf(hi) << 16);
}
__device__ inline float bf_lo(unsigned int v) { return __uint_as_float(v << 16); }
__device__ inline float bf_hi(unsigned int v) { return __uint_as_float(v & 0xffff0000u); }
__device__ inline float bf1(unsigned short v) { return __uint_as_float((unsigned int)v << 16); }

// ---------------- prep: weight cvt/transpose + zero cnt ----------------

__global__ __launch_bounds__(256) void prep(const float* __restrict__ W1,
                                            const float* __restrict__ W2,
                                            unsigned short* __restrict__ w1t,
                                            unsigned short* __restrict__ w2t,
                                            int* __restrict__ cnt, int n) {
  int idx = blockIdx.x * 256 + threadIdx.x;
  if (idx < FIN * HD) {
    int k = idx >> 7, c = idx & 127;
    w1t[(size_t)c * FIN + k] = f2bf(W1[idx]);
  } else if (idx < FIN * HD + HD * CD) {
    int j = idx - FIN * HD;
    int k = j >> 6, c = j & 63;
    w2t[(size_t)c * HD + k] = f2bf(W2[j]);
  }
  if (idx < n) cnt[idx] = 0;
}

// ---------------- deterministic 2-kernel scan (no inter-block sync) ----------------

__global__ __launch_bounds__(256) void scan_a(const int* __restrict__ cnt,
                                              int* __restrict__ bs, int n) {
  __shared__ int sh[256];
  int t = threadIdx.x;
  int base = blockIdx.x * 2048;
  int s = 0;
#pragma unroll
  for (int j = 0; j < 8; ++j) {
    int idx = base + j * 256 + t;
    if (idx < n) s += cnt[idx];
  }
  sh[t] = s;
  __syncthreads();
  for (int o = 128; o > 0; o >>= 1) {
    if (t < o) sh[t] += sh[t + o];
    __syncthreads();
  }
  if (t == 0) bs[blockIdx.x] = sh[0];
}

__global__ __launch_bounds__(256) void scan_c(const int* __restrict__ cnt,
                                              const int* __restrict__ bs,
                                              int* __restrict__ off,
                                              int* __restrict__ cur, int n) {
  __shared__ int sh[256];
  __shared__ int sbase;
  const int t   = threadIdx.x;
  const int bid = blockIdx.x;
  if (t < 64) {  // block offset = sum of earlier blocks' sums (bid <= 63)
    int v = (t < bid) ? bs[t] : 0;
#pragma unroll
    for (int o = 32; o > 0; o >>= 1) v += __shfl_xor(v, o, 64);
    if (t == 0) sbase = v;
  }
  const int base = bid * 2048 + t * 8;
  int v[8];
  int local = 0;
#pragma unroll
  for (int j = 0; j < 8; ++j) {
    v[j] = (base + j < n) ? cnt[base + j] : 0;
    local += v[j];
  }
  sh[t] = local;
  __syncthreads();
  for (int o = 1; o < 256; o <<= 1) {
    int u = (t >= o) ? sh[t - o] : 0;
    __syncthreads();
    sh[t] += u;
    __syncthreads();
  }
  int run = sbase + sh[t] - local;
#pragma unroll
  for (int j = 0; j < 8; ++j) {
    if (base + j < n) { off[base + j] = run; cur[base + j] = run; }
    run += v[j];
  }
}

// ---------------- shared gemm1 tile body (128x128 tile, BK=32, R0 shape) ----------------

__device__ __forceinline__ void gemm1_tile(const float* __restrict__ x,
                                           const unsigned short* __restrict__ w1t,
                                           unsigned short* __restrict__ h1b, int M,
                                           int tile,
                                           unsigned short (*As)[40],
                                           unsigned short (*Bs)[40]) {
  const int t    = threadIdx.x;
  const int wave = t >> 6;
  const int lane = t & 63;
  const int l15  = lane & 15;
  const int quad = lane >> 4;
  const int m0   = tile * 128;

  const int sr = t >> 1;        // staging row 0..127
  const int sk = (t & 1) * 16;  // staging k: 0 or 16

  const bool aok = (m0 + sr) < M;
  const float* xrow = x + (size_t)(m0 + sr) * FIN + sk;
  const unsigned short* brow = w1t + (size_t)sr * FIN + sk;

  f32x4 acc[2][8];
#pragma unroll
  for (int i = 0; i < 2; ++i)
#pragma unroll
    for (int j = 0; j < 8; ++j) acc[i][j] = (f32x4)0.f;

  for (int k0 = 0; k0 < FIN; k0 += 32) {
    float4 a0 = make_float4(0.f, 0.f, 0.f, 0.f), a1 = a0, a2 = a0, a3 = a0;
    if (aok) {
      a0 = *(const float4*)(xrow + k0);
      a1 = *(const float4*)(xrow + k0 + 4);
      a2 = *(const float4*)(xrow + k0 + 8);
      a3 = *(const float4*)(xrow + k0 + 12);
    }
    uint4 b0 = *(const uint4*)(brow + k0);
    uint4 b1 = *(const uint4*)(brow + k0 + 8);
    __syncthreads();
    uint4 av0, av1;   // register-only bf16 packing (no scratch array)
    av0.x = pk2(a0.x, a0.y); av0.y = pk2(a0.z, a0.w);
    av0.z = pk2(a1.x, a1.y); av0.w = pk2(a1.z, a1.w);
    av1.x = pk2(a2.x, a2.y); av1.y = pk2(a2.z, a2.w);
    av1.z = pk2(a3.x, a3.y); av1.w = pk2(a3.z, a3.w);
    *(uint4*)&As[sr][sk]     = av0;
    *(uint4*)&As[sr][sk + 8] = av1;
    *(uint4*)&Bs[sr][sk]     = b0;
    *(uint4*)&Bs[sr][sk + 8] = b1;
    __syncthreads();
    short8 af0 = *(const short8*)&As[wave * 32 + l15][quad * 8];
    short8 af1 = *(const short8*)&As[wave * 32 + 16 + l15][quad * 8];
#pragma unroll
    for (int nt = 0; nt < 8; ++nt) {
      short8 bf = *(const short8*)&Bs[nt * 16 + l15][quad * 8];
      acc[0][nt] = __builtin_amdgcn_mfma_f32_16x16x32_bf16(af0, bf, acc[0][nt], 0, 0, 0);
      acc[1][nt] = __builtin_amdgcn_mfma_f32_16x16x32_bf16(af1, bf, acc[1][nt], 0, 0, 0);
    }
  }
#pragma unroll
  for (int mt = 0; mt < 2; ++mt) {
    const int row0 = m0 + wave * 32 + mt * 16 + quad * 4;
#pragma unroll
    for (int r = 0; r < 4; ++r) {
      int row = row0 + r;
      if (row < M) {
        unsigned short* orow = h1b + (size_t)row * HD + l15;
#pragma unroll
        for (int nt = 0; nt < 8; ++nt) orow[nt * 16] = f2bf(acc[mt][nt][r]);
      }
    }
  }
}

// ---------------- K1: gemm1 tiles [0, ngemm) || hist ----------------

__global__ __launch_bounds__(256) void gemm1_hist(const float* __restrict__ x,
                                                  const unsigned short* __restrict__ w1t,
                                                  unsigned short* __restrict__ h1b, int M,
                                                  const int* __restrict__ dst, int E,
                                                  int* __restrict__ cnt, int ngemm) {
  __shared__ unsigned short As[128][40];
  __shared__ unsigned short Bs[128][40];
  if ((int)blockIdx.x >= ngemm) {   // hist role (uniform per block)
    int i = (blockIdx.x - ngemm) * 256 + threadIdx.x;
    if (i < E) atomicAdd(&cnt[dst[i]], 1);
    return;
  }
  gemm1_tile(x, w1t, h1b, M, blockIdx.x, As, Bs);
}

// ---------------- K4: gemm1 tiles [tile0, ntile) || scatter ----------------

__global__ __launch_bounds__(256) void gemm1_scat(const float* __restrict__ x,
                                                  const unsigned short* __restrict__ w1t,
                                                  unsigned short* __restrict__ h1b, int M,
                                                  const int* __restrict__ src,
                                                  const int* __restrict__ dst,
                                                  const float* __restrict__ ew, int E,
                                                  int* __restrict__ cur,
                                                  int2* __restrict__ sew,
                                                  int tile0, int ngemm) {
  __shared__ unsigned short As[128][40];
  __shared__ unsigned short Bs[128][40];
  if ((int)blockIdx.x >= ngemm) {   // scatter role (uniform per block)
    int i = (blockIdx.x - ngemm) * 256 + threadIdx.x;
    if (i < E) {
      int d = dst[i];
      int p = atomicAdd(&cur[d], 1);
      sew[p] = make_int2(src[i], __float_as_int(ew[i]));
    }
    return;
  }
  gemm1_tile(x, w1t, h1b, M, tile0 + blockIdx.x, As, Bs);
}

// ---------------- agg1: wave/node (max TLP), 8-deep unroll, bf16 in/out ----------------

__global__ __launch_bounds__(256) void agg1_kernel(const unsigned int* __restrict__ h1b,
                                                   const float* __restrict__ b1,
                                                   const float* __restrict__ dm,
                                                   const int* __restrict__ off,
                                                   const int* __restrict__ cnt,
                                                   const int2* __restrict__ sew,
                                                   unsigned int* __restrict__ hbf, int N) {
  const int wave = threadIdx.x >> 6;
  const int lane = threadIdx.x & 63;
  const int node = blockIdx.x * 4 + wave;
  if (node >= N) return;
  const int start = off[node];
  const int deg   = cnt[node];
  const int2* ep  = sew + start;

  float a0 = 0.f, a1 = 0.f, c0 = 0.f, c1 = 0.f;
  float e0 = 0.f, e1 = 0.f, g0 = 0.f, g1 = 0.f;
  int e = 0;
  for (; e + 8 <= deg; e += 8) {
    int2 p0 = ep[e + 0], p1 = ep[e + 1], p2 = ep[e + 2], p3 = ep[e + 3];
    int2 p4 = ep[e + 4], p5 = ep[e + 5], p6 = ep[e + 6], p7 = ep[e + 7];
    unsigned int v0 = h1b[(size_t)p0.x * 64 + lane];
    unsigned int v1 = h1b[(size_t)p1.x * 64 + lane];
    unsigned int v2 = h1b[(size_t)p2.x * 64 + lane];
    unsigned int v3 = h1b[(size_t)p3.x * 64 + lane];
    unsigned int v4 = h1b[(size_t)p4.x * 64 + lane];
    unsigned int v5 = h1b[(size_t)p5.x * 64 + lane];
    unsigned int v6 = h1b[(size_t)p6.x * 64 + lane];
    unsigned int v7 = h1b[(size_t)p7.x * 64 + lane];
    float w0 = __int_as_float(p0.y), w1 = __int_as_float(p1.y);
    float w2 = __int_as_float(p2.y), w3 = __int_as_float(p3.y);
    float w4 = __int_as_float(p4.y), w5 = __int_as_float(p5.y);
    float w6 = __int_as_float(p6.y), w7 = __int_as_float(p7.y);
    a0 = fmaf(bf_lo(v0), w0, a0); a1 = fmaf(bf_hi(v0), w0, a1);
    c0 = fmaf(bf_lo(v1), w1, c0); c1 = fmaf(bf_hi(v1), w1, c1);
    e0 = fmaf(bf_lo(v2), w2, e0); e1 = fmaf(bf_hi(v2), w2, e1);
    g0 = fmaf(bf_lo(v3), w3, g0); g1 = fmaf(bf_hi(v3), w3, g1);
    a0 = fmaf(bf_lo(v4), w4, a0); a1 = fmaf(bf_hi(v4), w4, a1);
    c0 = fmaf(bf_lo(v5), w5, c0); c1 = fmaf(bf_hi(v5), w5, c1);
    e0 = fmaf(bf_lo(v6), w6, e0); e1 = fmaf(bf_hi(v6), w6, e1);
    g0 = fmaf(bf_lo(v7), w7, g0); g1 = fmaf(bf_hi(v7), w7, g1);
  }
  for (; e + 4 <= deg; e += 4) {
    int2 p0 = ep[e + 0], p1 = ep[e + 1], p2 = ep[e + 2], p3 = ep[e + 3];
    unsigned int v0 = h1b[(size_t)p0.x * 64 + lane];
    unsigned int v1 = h1b[(size_t)p1.x * 64 + lane];
    unsigned int v2 = h1b[(size_t)p2.x * 64 + lane];
    unsigned int v3 = h1b[(size_t)p3.x * 64 + lane];
    float w0 = __int_as_float(p0.y), w1 = __int_as_float(p1.y);
    float w2 = __int_as_float(p2.y), w3 = __int_as_float(p3.y);
    a0 = fmaf(bf_lo(v0), w0, a0); a1 = fmaf(bf_hi(v0), w0, a1);
    c0 = fmaf(bf_lo(v1), w1, c0); c1 = fmaf(bf_hi(v1), w1, c1);
    e0 = fmaf(bf_lo(v2), w2, e0); e1 = fmaf(bf_hi(v2), w2, e1);
    g0 = fmaf(bf_lo(v3), w3, g0); g1 = fmaf(bf_hi(v3), w3, g1);
  }
  for (; e < deg; ++e) {
    int2 p = ep[e];
    unsigned int v = h1b[(size_t)p.x * 64 + lane];
    float w = __int_as_float(p.y);
    a0 = fmaf(bf_lo(v), w, a0); a1 = fmaf(bf_hi(v), w, a1);
  }
  a0 += c0 + e0 + g0; a1 += c1 + e1 + g1;

  const int f0 = lane * 2;
  float2 bb = *(const float2*)(b1 + f0);
  float2 dd = *(const float2*)(dm + (size_t)node * HD + f0);
  float r0 = fmaxf(a0 + bb.x, 0.f) * ((dd.x >= 0.5f) ? 2.0f : 0.0f);
  float r1 = fmaxf(a1 + bb.y, 0.f) * ((dd.y >= 0.5f) ? 2.0f : 0.0f);
  hbf[(size_t)node * 64 + lane] = (unsigned int)f2bf(r0) | ((unsigned int)f2bf(r1) << 16);
}

// ---------------- GEMM2 (MFMA bf16): h2b[M,64](bf16) = h_bf[M,128] @ W2 ----------------

__global__ __launch_bounds__(256) void gemm2_mfma(const unsigned short* __restrict__ hbf,
                                                  const unsigned short* __restrict__ w2t,
                                                  unsigned short* __restrict__ h2b, int M) {
  __shared__ unsigned short As[128][40];
  __shared__ unsigned short Bs[64][40];
  const int t    = threadIdx.x;
  const int wave = t >> 6;
  const int lane = t & 63;
  const int l15  = lane & 15;
  const int quad = lane >> 4;
  const int m0   = blockIdx.x * 128;

  const int sr = t >> 1;        // A staging row 0..127
  const int sk = (t & 1) * 16;
  const int rb = t >> 2;        // B staging row 0..63
  const int kb = (t & 3) * 8;   // 4 threads x 8 ushorts = 32

  const bool aok = (m0 + sr) < M;
  const unsigned short* arow = hbf + (size_t)(m0 + sr) * HD + sk;
  const unsigned short* brow = w2t + (size_t)rb * HD + kb;

  f32x4 acc[2][4];
#pragma unroll
  for (int i = 0; i < 2; ++i)
#pragma unroll
    for (int j = 0; j < 4; ++j) acc[i][j] = (f32x4)0.f;

  for (int k0 = 0; k0 < HD; k0 += 32) {
    uint4 av0 = make_uint4(0, 0, 0, 0), av1 = av0;
    if (aok) {
      av0 = *(const uint4*)(arow + k0);
      av1 = *(const uint4*)(arow + k0 + 8);
    }
    uint4 bv = *(const uint4*)(brow + k0);   // 8 ushorts
    __syncthreads();
    *(uint4*)&As[sr][sk]     = av0;
    *(uint4*)&As[sr][sk + 8] = av1;
    *(uint4*)&Bs[rb][kb]     = bv;
    __syncthreads();
    short8 af0 = *(const short8*)&As[wave * 32 + l15][quad * 8];
    short8 af1 = *(const short8*)&As[wave * 32 + 16 + l15][quad * 8];
#pragma unroll
    for (int nt = 0; nt < 4; ++nt) {
      short8 bf = *(const short8*)&Bs[nt * 16 + l15][quad * 8];
      acc[0][nt] = __builtin_amdgcn_mfma_f32_16x16x32_bf16(af0, bf, acc[0][nt], 0, 0, 0);
      acc[1][nt] = __builtin_amdgcn_mfma_f32_16x16x32_bf16(af1, bf, acc[1][nt], 0, 0, 0);
    }
  }
#pragma unroll
  for (int mt = 0; mt < 2; ++mt) {
    const int row0 = m0 + wave * 32 + mt * 16 + quad * 4;
#pragma unroll
    for (int r = 0; r < 4; ++r) {
      int row = row0 + r;
      if (row < M) {
        unsigned short* orow = h2b + (size_t)row * CD + l15;
#pragma unroll
        for (int nt = 0; nt < 4; ++nt) orow[nt * 16] = f2bf(acc[mt][nt][r]);
      }
    }
  }
}

// ---------------- agg2 + bias + log_softmax: wave/node, 8-deep unroll ----------------

__global__ __launch_bounds__(256) void agg2_kernel(const unsigned short* __restrict__ h2b,
                                                   const float* __restrict__ b2,
                                                   const int* __restrict__ off,
                                                   const int* __restrict__ cnt,
                                                   const int2* __restrict__ sew,
                                                   float* __restrict__ out, int N) {
  const int wave = threadIdx.x >> 6;
  const int c    = threadIdx.x & 63;
  const int node = blockIdx.x * 4 + wave;
  if (node >= N) return;
  const int start = off[node];
  const int deg   = cnt[node];
  const int2* ep  = sew + start;

  float acc = b2[c], a1 = 0.f, a2 = 0.f, a3 = 0.f;
  int e = 0;
  for (; e + 8 <= deg; e += 8) {
    int2 p0 = ep[e + 0], p1 = ep[e + 1], p2 = ep[e + 2], p3 = ep[e + 3];
    int2 p4 = ep[e + 4], p5 = ep[e + 5], p6 = ep[e + 6], p7 = ep[e + 7];
    float v0 = bf1(h2b[(size_t)p0.x * CD + c]);
    float v1 = bf1(h2b[(size_t)p1.x * CD + c]);
    float v2 = bf1(h2b[(size_t)p2.x * CD + c]);
    float v3 = bf1(h2b[(size_t)p3.x * CD + c]);
    float v4 = bf1(h2b[(size_t)p4.x * CD + c]);
    float v5 = bf1(h2b[(size_t)p5.x * CD + c]);
    float v6 = bf1(h2b[(size_t)p6.x * CD + c]);
    float v7 = bf1(h2b[(size_t)p7.x * CD + c]);
    acc = fmaf(v0, __int_as_float(p0.y), acc);
    a1  = fmaf(v1, __int_as_float(p1.y), a1);
    a2  = fmaf(v2, __int_as_float(p2.y), a2);
    a3  = fmaf(v3, __int_as_float(p3.y), a3);
    acc = fmaf(v4, __int_as_float(p4.y), acc);
    a1  = fmaf(v5, __int_as_float(p5.y), a1);
    a2  = fmaf(v6, __int_as_float(p6.y), a2);
    a3  = fmaf(v7, __int_as_float(p7.y), a3);
  }
  for (; e + 4 <= deg; e += 4) {
    int2 p0 = ep[e + 0], p1 = ep[e + 1], p2 = ep[e + 2], p3 = ep[e + 3];
    float v0 = bf1(h2b[(size_t)p0.x * CD + c]);
    float v1 = bf1(h2b[(size_t)p1.x * CD + c]);
    float v2 = bf1(h2b[(size_t)p2.x * CD + c]);
    float v3 = bf1(h2b[(size_t)p3.x * CD + c]);
    acc = fmaf(v0, __int_as_float(p0.y), acc);
    a1  = fmaf(v1, __int_as_float(p1.y), a1);
    a2  = fmaf(v2, __int_as_float(p2.y), a2);
    a3  = fmaf(v3, __int_as_float(p3.y), a3);
  }
  for (; e < deg; ++e) {
    int2 p = ep[e];
    acc = fmaf(bf1(h2b[(size_t)p.x * CD + c]), __int_as_float(p.y), acc);
  }
  acc += a1 + a2 + a3;

  float m = acc;
#pragma unroll
  for (int o = 32; o > 0; o >>= 1) m = fmaxf(m, __shfl_xor(m, o, 64));
  float ex = __expf(acc - m);
  float ssum = ex;
#pragma unroll
  for (int o = 32; o > 0; o >>= 1) ssum += __shfl_xor(ssum, o, 64);
  out[(size_t)node * CD + c] = (acc - m) - __logf(ssum);
}

// ---------------- launch ----------------

extern "C" void kernel_launch(void* const* d_in, const int* in_sizes, int n_in,
                              void* d_out, int out_size, void* d_ws, size_t ws_size,
                              hipStream_t stream) {
  const float* x  = (const float*)d_in[0];
  const float* ew = (const float*)d_in[1];
  const float* W1 = (const float*)d_in[2];
  const float* b1 = (const float*)d_in[3];
  const float* W2 = (const float*)d_in[4];
  const float* b2 = (const float*)d_in[5];
  const float* dm = (const float*)d_in[6];
  const int*   ei = (const int*)d_in[7];
  float* out = (float*)d_out;

  const int E = in_sizes[1];
  const int N = in_sizes[6] / HD;
  const int* srcp = ei;
  const int* dstp = ei + E;
  const int nb = (N + 2047) / 2048;  // 25 scan blocks (<=64 supported by scan_c)

  uint8_t* w = (uint8_t*)d_ws;
  size_t o = 0;
  auto alloc = [&](size_t bytes) -> void* {
    void* p = w + o;
    o = (o + bytes + 255) & ~(size_t)255;
    return p;
  };
  int*   off    = (int*)alloc((size_t)N * 4);
  int*   cnt    = (int*)alloc((size_t)N * 4);
  int*   cur    = (int*)alloc((size_t)N * 4);
  int2*  sew    = (int2*)alloc((size_t)E * 8);
  unsigned short* h1b = (unsigned short*)alloc((size_t)N * HD * 2);
  unsigned int*   hbf = (unsigned int*)alloc((size_t)N * HD * 2);
  unsigned short* h2b = (unsigned short*)alloc((size_t)N * CD * 2);
  unsigned short* w1t = (unsigned short*)alloc((size_t)FIN * HD * 2);
  unsigned short* w2t = (unsigned short*)alloc((size_t)HD * CD * 2);
  int*   bsum   = (int*)alloc((size_t)nb * 4);

  const int prep_threads = FIN * HD + HD * CD;  // covers N zeroing too (73728 > 50000)
  prep<<<(prep_threads + 255) / 256, 256, 0, stream>>>(W1, W2, w1t, w2t, cnt, N);

  const int ntile  = (N + 127) / 128;   // 391 gemm tiles total
  const int ntileA = ntile / 2;         // 195 tiles in K1
  const int ntileB = ntile - ntileA;    // 196 tiles in K4
  const int nedge  = (E + 255) / 256;   // 3125 edge blocks

  // K1: gemm1 first half || hist
  gemm1_hist<<<ntileA + nedge, 256, 0, stream>>>(x, w1t, h1b, N, dstp, E, cnt, ntileA);
  scan_a<<<nb, 256, 0, stream>>>(cnt, bsum, N);
  scan_c<<<nb, 256, 0, stream>>>(cnt, bsum, off, cur, N);
  // K4: gemm1 second half || scatter
  gemm1_scat<<<ntileB + nedge, 256, 0, stream>>>(x, w1t, h1b, N, srcp, dstp, ew, E,
                                                 cur, sew, ntileA, ntileB);
  agg1_kernel<<<(N + 3) / 4, 256, 0, stream>>>((const unsigned int*)h1b, b1, dm, off, cnt, sew, hbf, N);
  gemm2_mfma<<<(N + 127) / 128, 256, 0, stream>>>((const unsigned short*)hbf, w2t, h2b, N);
  agg2_kernel<<<(N + 3) / 4, 256, 0, stream>>>(h2b, b2, off, cnt, sew, out, N);
}